// Round 13
// baseline (98.764 us; speedup 1.0000x reference)
//
#include <hip/hip_runtime.h>

// NestedAttention MI355X round 13: occupancy push — attn at launch_bounds
// (256,5) (20 waves/CU >= 20.25 demand, kills the 27% batch tail). Register
// diet to fit the 102-reg cap: single K-frag set reloaded after its QK use
// (prefetch depth 1, zero extra regs). Everything else = round 12.
//
// ws layout (ushort elems):
//   Qf  [3i][4b][72 t][4 f][512]     @ OQ
//   Kf  [3i][4b][72 t][4 f][512]     @ OK_
//   Vf  [3i][4b][72 t][2c][2rb][512] @ OV
//   combjf [3j][4b][72 nt][12 ks][512] @ OC (+j*CSTR)  (B-frag chunks)
//   xf  [4b][72 nb][16 ks][512]      @ OXF
//   Wf  [9 s][16 ks][2 rb][512]      @ OWF
//   WoF [12 ks][8 rb][512]           @ OWOF
// Frag chunk: chunk[lane*8+e] = Op[idx=lane&31][k=8*(lane>>5)+e]

#define BB 4
#define CC 256
#define NN_ 2304
#define RR 64

#define OQ 0
#define OK_ 1769472
#define OV 3538944
#define OC 5308416
#define CSTR 1769472
#define FR_IB 147456
#define OXF 10616832
#define OWF 12976128
#define OWOF 13123584

typedef __bf16 bf16x8 __attribute__((ext_vector_type(8)));
typedef float f32x16 __attribute__((ext_vector_type(16)));
typedef unsigned short ushort8 __attribute__((ext_vector_type(8)));
typedef unsigned int uintx2 __attribute__((ext_vector_type(2)));
typedef unsigned int uintx4 __attribute__((ext_vector_type(4)));

#if __has_builtin(__builtin_amdgcn_exp2f)
#define EXP2(x) __builtin_amdgcn_exp2f(x)
#else
#define EXP2(x) exp2f(x)
#endif

__device__ __forceinline__ float bf2f(unsigned short s) {
    unsigned int u = ((unsigned int)s) << 16;
    return __builtin_bit_cast(float, u);
}
__device__ __forceinline__ unsigned int pk_bf16(float lo, float hi) {
    unsigned int r;
    asm("v_cvt_pk_bf16_f32 %0, %1, %2" : "=v"(r) : "v"(lo), "v"(hi));
    return r;
}

// ---------------------------------------------------------------------------
// Prep: bid<9 weights->A-frags; bid<12 wo->A-frags; else x->B-frags.
// ---------------------------------------------------------------------------
__global__ __launch_bounds__(256) void prep_kernel(
    const float* __restrict__ x, const float* __restrict__ wq,
    const float* __restrict__ wk, const float* __restrict__ wv,
    const float* __restrict__ wo, unsigned short* __restrict__ wsb)
{
    int bid = blockIdx.x;
    int t = threadIdx.x;
    if (bid < 9) {
        int s = bid;
        int type = s / 3, i = s % 3;
        const float* wsel = (type == 0) ? wq : (type == 1 ? wk : wv);
        const float scale = (type == 0) ? 0.18033688011112042f : 1.0f;  // 0.125*log2e
        unsigned short* dst = wsb + OWF + s * 16384;
        #pragma unroll
        for (int p = 0; p < 8; ++p) {
            int u = t + 256 * p;
            int ks = u >> 7, rb = (u >> 6) & 1, lo = u & 63;
            int row = rb * 32 + (lo & 31), c = ks * 16 + 8 * (lo >> 5);
            const float* src = wsel + ((i * 64 + row) * 256 + c);
            float4 f0 = *(const float4*)(src);
            float4 f1 = *(const float4*)(src + 4);
            uintx4 pwv = {pk_bf16(f0.x * scale, f0.y * scale),
                          pk_bf16(f0.z * scale, f0.w * scale),
                          pk_bf16(f1.x * scale, f1.y * scale),
                          pk_bf16(f1.z * scale, f1.w * scale)};
            *(uintx4*)(dst + (ks * 2 + rb) * 512 + lo * 8) = pwv;
        }
        return;
    }
    if (bid < 12) {
        int bb = bid - 9;
        #pragma unroll
        for (int p = 0; p < 8; ++p) {
            int u = t + 256 * p;
            int cg = bb * 32 + (u >> 6);
            int lane = u & 63;
            int ks = cg >> 3, rb = cg & 7;
            int row = rb * 32 + (lane & 31);
            int g = ks * 16 + 8 * (lane >> 5);
            const float* src = wo + row * 192 + g;
            float4 f0 = *(const float4*)(src);
            float4 f1 = *(const float4*)(src + 4);
            uintx4 pwv = {pk_bf16(f0.x, f0.y), pk_bf16(f0.z, f0.w),
                          pk_bf16(f1.x, f1.y), pk_bf16(f1.z, f1.w)};
            *(uintx4*)(wsb + OWOF + cg * 512 + lane * 8) = pwv;
        }
        return;
    }
    __shared__ __align__(16) float xs[64 * 132];
    int xb = bid - 12;
    int cq  = xb & 3;
    int nt2 = (xb >> 2) % 18;
    int b   = xb / 72;
    int c0 = cq * 64, n0 = nt2 * 128;
    #pragma unroll
    for (int p = 0; p < 8; ++p) {
        int u = t + 256 * p;
        int cl = u >> 5, nq = (u & 31) * 4;
        *(float4*)&xs[cl * 132 + nq] =
            *(const float4*)&x[((size_t)(b * CC + c0 + cl)) * NN_ + n0 + nq];
    }
    __syncthreads();
    unsigned short* xfb = wsb + OXF + ((size_t)b) * 72 * 16 * 512;
    #pragma unroll
    for (int p = 0; p < 4; ++p) {
        int u = t + 256 * p;
        int nb_l = u >> 8, ks_l = (u >> 6) & 3, lo = u & 63;
        int hh = lo >> 5, idx = lo & 31;
        int clb = ks_l * 16 + 8 * hh;
        int nn = nb_l * 32 + idx;
        unsigned int pw[4];
        #pragma unroll
        for (int d = 0; d < 4; ++d) {
            float a  = xs[(clb + 2 * d) * 132 + nn];
            float bb2 = xs[(clb + 2 * d + 1) * 132 + nn];
            pw[d] = pk_bf16(a, bb2);
        }
        int nb = nt2 * 4 + nb_l, ks = cq * 4 + ks_l;
        *(uintx4*)(xfb + (nb * 16 + ks) * 512 + lo * 8) =
            (uintx4){pw[0], pw[1], pw[2], pw[3]};
    }
}

// ---------------------------------------------------------------------------
// Kernel: MFMA projection (unchanged structure).
// ---------------------------------------------------------------------------
__global__ __launch_bounds__(256) void proj_mfma(unsigned short* __restrict__ wsb)
{
    int bid = blockIdx.x;
    int s = bid / 72;
    int rem = bid % 72;
    int b = rem / 18, nb4 = rem % 18;
    int type = s / 3, i = s % 3;
    int t = threadIdx.x;
    int w = t >> 6, lane = t & 63;
    int lq = lane & 31, h = lane >> 5;
    int nb = nb4 * 4 + w;

    const unsigned short* wf = wsb + OWF + s * 16384 + lane * 8;
    const unsigned short* xf = wsb + OXF + ((size_t)(b * 72 + nb) * 16) * 512 + lane * 8;

    f32x16 o0 = {}, o1 = {};
    if (type < 2) {
        #pragma unroll
        for (int ks = 0; ks < 16; ++ks) {
            bf16x8 a0 = *(const bf16x8*)(wf + ks * 1024);
            bf16x8 a1 = *(const bf16x8*)(wf + ks * 1024 + 512);
            bf16x8 bx = *(const bf16x8*)(xf + ks * 512);
            o0 = __builtin_amdgcn_mfma_f32_32x32x16_bf16(a0, bx, o0, 0, 0, 0);
            o1 = __builtin_amdgcn_mfma_f32_32x32x16_bf16(a1, bx, o1, 0, 0, 0);
        }
    } else {
        #pragma unroll
        for (int ks = 0; ks < 16; ++ks) {
            bf16x8 a0 = *(const bf16x8*)(wf + ks * 1024);
            bf16x8 a1 = *(const bf16x8*)(wf + ks * 1024 + 512);
            bf16x8 bx = *(const bf16x8*)(xf + ks * 512);
            o0 = __builtin_amdgcn_mfma_f32_32x32x16_bf16(bx, a0, o0, 0, 0, 0);
            o1 = __builtin_amdgcn_mfma_f32_32x32x16_bf16(bx, a1, o1, 0, 0, 0);
        }
    }

    unsigned short* dstbase =
        wsb + ((type == 0) ? OQ : (type == 1 ? OK_ : OV)) +
        ((size_t)(i * 4 + b)) * FR_IB + nb * 2048;

    if (type < 2) {
        #pragma unroll
        for (int g = 0; g < 4; ++g) {
            int kd = 8 * g + 4 * h;
            int off = (kd >> 4) * 512 + ((kd >> 3) & 1) * 256 + lq * 8 + (kd & 7);
            *(uintx2*)(dstbase + off) =
                (uintx2){pk_bf16(o0[4 * g], o0[4 * g + 1]),
                         pk_bf16(o0[4 * g + 2], o0[4 * g + 3])};
            int kd2 = kd + 32;
            int off2 = (kd2 >> 4) * 512 + ((kd2 >> 3) & 1) * 256 + lq * 8 + (kd2 & 7);
            *(uintx2*)(dstbase + off2) =
                (uintx2){pk_bf16(o1[4 * g], o1[4 * g + 1]),
                         pk_bf16(o1[4 * g + 2], o1[4 * g + 3])};
        }
    } else {
        #pragma unroll
        for (int g = 0; g < 4; ++g) {
            int off = (g >> 1) * 1024 + (g & 1) * 256 + lq * 8 + 4 * h;
            *(uintx2*)(dstbase + off) =
                (uintx2){pk_bf16(o0[4 * g], o0[4 * g + 1]),
                         pk_bf16(o0[4 * g + 2], o0[4 * g + 3])};
            *(uintx2*)(dstbase + off + 512) =
                (uintx2){pk_bf16(o1[4 * g], o1[4 * g + 1]),
                         pk_bf16(o1[4 * g + 2], o1[4 * g + 3])};
        }
    }
}

// ---------------------------------------------------------------------------
// Kernel: barrier-free MFMA flash attention at 5 waves/SIMD.
// Block = 4 waves = 2 q-tiles x 2 key-halves. K: single reg set, reloaded
// for step+1 immediately after its QK use (prefetch depth 1, 0 extra regs).
// V just-in-time. l via VALU add-tree. Epilogue = rounds 11/12.
// ---------------------------------------------------------------------------
__global__ __launch_bounds__(256, 5) void attn_kernel(unsigned short* __restrict__ wsb)
{
    __shared__ __align__(16) float fl[4352];

    int bid = blockIdx.x;
    int wid = (bid & 7) * 162 + (bid >> 3);   // XCD-contiguous (1296 = 8*162)
    int s12 = wid / 108;
    int rem = wid % 108;
    int j = s12 >> 2, b = s12 & 3;
    int i = rem / 36;
    int qp = rem % 36;
    int w = threadIdx.x >> 6;
    int ks = w & 1, qloc = w >> 1;
    int lane = threadIdx.x & 63;
    int lq = lane & 31;
    int h = lane >> 5;
    int q0 = (qp * 2 + qloc) * 32;
    int nt = q0 >> 5;

    const unsigned short* qtf = wsb + OQ + ((size_t)(i * 4 + b)) * FR_IB +
                                nt * 2048 + lane * 8;
    const unsigned short* kp = wsb + OK_ + ((size_t)(j * 4 + b)) * FR_IB +
                               (size_t)(ks * 36) * 2048 + lane * 8;
    const unsigned short* vp = wsb + OV + ((size_t)(j * 4 + b)) * FR_IB +
                               (size_t)(ks * 36) * 2048 + lane * 8;

    bf16x8 bq0 = *(const bf16x8*)(qtf + 0);
    bf16x8 bq1 = *(const bf16x8*)(qtf + 512);
    bf16x8 bq2 = *(const bf16x8*)(qtf + 1024);
    bf16x8 bq3 = *(const bf16x8*)(qtf + 1536);

    f32x16 o0 = {}, o1 = {};
    float l_loc = 0.f;

    // preload K for step 0
    bf16x8 k0 = *(const bf16x8*)(kp + 0 * 512);
    bf16x8 k1 = *(const bf16x8*)(kp + 1 * 512);
    bf16x8 k2 = *(const bf16x8*)(kp + 2 * 512);
    bf16x8 k3 = *(const bf16x8*)(kp + 3 * 512);

    for (int step = 0; step < 36; ++step) {
        // V just-in-time: lands under QK+exp
        const unsigned short* vb = vp + (size_t)step * 2048;
        bf16x8 v00 = *(const bf16x8*)(vb + 0 * 512);  // c0,rb0
        bf16x8 v10 = *(const bf16x8*)(vb + 1 * 512);  // c0,rb1
        bf16x8 v01 = *(const bf16x8*)(vb + 2 * 512);  // c1,rb0
        bf16x8 v11 = *(const bf16x8*)(vb + 3 * 512);  // c1,rb1

        f32x16 s = {};
        s = __builtin_amdgcn_mfma_f32_32x32x16_bf16(k0, bq0, s, 0, 0, 0);
        s = __builtin_amdgcn_mfma_f32_32x32x16_bf16(k1, bq1, s, 0, 0, 0);
        s = __builtin_amdgcn_mfma_f32_32x32x16_bf16(k2, bq2, s, 0, 0, 0);
        s = __builtin_amdgcn_mfma_f32_32x32x16_bf16(k3, bq3, s, 0, 0, 0);

        // K regs dead after QK issue -> reload same regs for step+1
        {
            int nx = (step + 1 < 36) ? (step + 1) : 0;
            const unsigned short* kb = kp + (size_t)nx * 2048;
            k0 = *(const bf16x8*)(kb + 0 * 512);
            k1 = *(const bf16x8*)(kb + 1 * 512);
            k2 = *(const bf16x8*)(kb + 2 * 512);
            k3 = *(const bf16x8*)(kb + 3 * 512);
        }

        // raw v_exp_f32 — inputs bounded (|S|log2e <= ~12)
        #pragma unroll
        for (int r = 0; r < 16; ++r) s[r] = EXP2(s[r]);
        l_loc += ((s[0] + s[1]) + (s[2] + s[3])) + ((s[4] + s[5]) + (s[6] + s[7])) +
                 ((s[8] + s[9]) + (s[10] + s[11])) + ((s[12] + s[13]) + (s[14] + s[15]));

        {   // keys 0..15
            unsigned int a0 = pk_bf16(s[0], s[1]);
            unsigned int a1 = pk_bf16(s[2], s[3]);
            unsigned int b0 = pk_bf16(s[4], s[5]);
            unsigned int b1 = pk_bf16(s[6], s[7]);
            uintx2 r0 = __builtin_amdgcn_permlane32_swap(a0, b0, false, false);
            uintx2 r1 = __builtin_amdgcn_permlane32_swap(a1, b1, false, false);
            uintx4 pwv = {r0[0], r1[0], r0[1], r1[1]};
            bf16x8 pa = __builtin_bit_cast(bf16x8, pwv);
            o0 = __builtin_amdgcn_mfma_f32_32x32x16_bf16(v00, pa, o0, 0, 0, 0);
            o1 = __builtin_amdgcn_mfma_f32_32x32x16_bf16(v10, pa, o1, 0, 0, 0);
        }
        {   // keys 16..31
            unsigned int a0 = pk_bf16(s[8], s[9]);
            unsigned int a1 = pk_bf16(s[10], s[11]);
            unsigned int b0 = pk_bf16(s[12], s[13]);
            unsigned int b1 = pk_bf16(s[14], s[15]);
            uintx2 r0 = __builtin_amdgcn_permlane32_swap(a0, b0, false, false);
            uintx2 r1 = __builtin_amdgcn_permlane32_swap(a1, b1, false, false);
            uintx4 pwv = {r0[0], r1[0], r0[1], r1[1]};
            bf16x8 pa = __builtin_bit_cast(bf16x8, pwv);
            o0 = __builtin_amdgcn_mfma_f32_32x32x16_bf16(v01, pa, o0, 0, 0, 0);
            o1 = __builtin_amdgcn_mfma_f32_32x32x16_bf16(v11, pa, o1, 0, 0, 0);
        }
    }

    float l_full = l_loc + __shfl_xor(l_loc, 32);

    // ---- combine ks halves: O = (O0+O1)/(l0+l1) ----
    int off = qloc * 2112;
    if (ks == 1) {
        #pragma unroll
        for (int reg = 0; reg < 16; ++reg) {
            fl[off + reg * 64 + lane] = o0[reg];
            fl[off + 1024 + reg * 64 + lane] = o1[reg];
        }
        fl[off + 2048 + lane] = l_full;
    }
    __syncthreads();
    if (ks == 1) return;

    #pragma unroll
    for (int reg = 0; reg < 16; ++reg) {
        o0[reg] += fl[off + reg * 64 + lane];
        o1[reg] += fl[off + 1024 + reg * 64 + lane];
    }
    float l_tot = l_full + fl[off + 2048 + lane];
    __syncthreads();   // fl reusable

    float inv = 1.f / l_tot;
    o0 *= inv; o1 *= inv;

    // transpose O^T -> per-query rows, then write comb as B-frag chunks
    float* tw = fl + qloc * 2080;
    #pragma unroll
    for (int reg = 0; reg < 16; ++reg) {
        int rv = (reg & 3) + 8 * (reg >> 2) + 4 * h;
        tw[lq * 65 + rv] = o0[reg];
        tw[lq * 65 + 32 + rv] = o1[reg];
    }
    // chunk[lane*8+e] = comb[n=q0+(lane&31)][g = i*64 + ksl*16 + 8h + e]
    unsigned short* cb = wsb + OC + (size_t)j * CSTR +
                         ((size_t)((b * 72 + nt) * 12 + i * 4)) * 512;
    #pragma unroll
    for (int ksl = 0; ksl < 4; ++ksl) {
        const float* src = tw + lq * 65 + ksl * 16 + 8 * h;
        uintx4 pwv = {pk_bf16(src[0], src[1]), pk_bf16(src[2], src[3]),
                      pk_bf16(src[4], src[5]), pk_bf16(src[6], src[7])};
        *(uintx4*)(cb + ksl * 512 + lane * 8) = pwv;
    }
}

// ---------------------------------------------------------------------------
// Kernel: MFMA out-projection + sigmoid gate.
// ---------------------------------------------------------------------------
__global__ __launch_bounds__(256) void out_mfma(
    const float* __restrict__ x, const unsigned short* __restrict__ wsb,
    float* __restrict__ out)
{
    int bid = blockIdx.x;
    int ch = bid & 1;
    int nt = (bid >> 1) % 72;
    int b  = bid / 144;
    int n0 = nt * 32;
    int t = threadIdx.x;
    int w = t >> 6, lane = t & 63;
    int lq = lane & 31, h = lane >> 5;
    int rb = ch * 4 + w;

    const unsigned short* wof = wsb + OWOF + lane * 8;
    const unsigned short* cbase = wsb + OC +
        ((size_t)((b * 72 + nt) * 12)) * 512 + lane * 8;

    f32x16 acc = {};
    #pragma unroll
    for (int j = 0; j < 3; ++j) {
        const unsigned short* cj = cbase + (size_t)j * CSTR;
        #pragma unroll
        for (int ksx = 0; ksx < 12; ++ksx) {
            bf16x8 bx = *(const bf16x8*)(cj + ksx * 512);
            bf16x8 a0 = *(const bf16x8*)(wof + (ksx * 8 + rb) * 512);
            acc = __builtin_amdgcn_mfma_f32_32x32x16_bf16(a0, bx, acc, 0, 0, 0);
        }
    }

    int c0 = rb * 32;
    #pragma unroll
    for (int reg = 0; reg < 16; ++reg) {
        int c = c0 + (reg & 3) + 8 * (reg >> 2) + 4 * h;
        size_t idx = ((size_t)(b * CC + c)) * NN_ + n0 + lq;
        float sg = 1.f / (1.f + EXP2(acc[reg] * -1.44269504f));
        out[idx] = x[idx] * sg;
    }
}

extern "C" void kernel_launch(void* const* d_in, const int* in_sizes, int n_in,
                              void* d_out, int out_size, void* d_ws, size_t ws_size,
                              hipStream_t stream) {
    const float* x  = (const float*)d_in[0];
    const float* wq = (const float*)d_in[1];
    const float* wk = (const float*)d_in[2];
    const float* wv = (const float*)d_in[3];
    const float* wo = (const float*)d_in[4];
    unsigned short* wsb = (unsigned short*)d_ws;
    float* out = (float*)d_out;

    prep_kernel<<<300, 256, 0, stream>>>(x, wq, wk, wv, wo, wsb);
    proj_mfma<<<648, 256, 0, stream>>>(wsb);
    attn_kernel<<<1296, 256, 0, stream>>>(wsb);
    out_mfma<<<576, 256, 0, stream>>>(x, wsb, out);
}

// Round 14
// 97.351 us; speedup vs baseline: 1.0145x; 1.0145x over previous
//
#include <hip/hip_runtime.h>

// NestedAttention MI355X round 14: schedule-evening. attn = 8-way key-split,
// block = 8 waves x 9 steps (512 thr, 2 blocks/CU, 5.06 fine refills vs 1.27
// coarse), cap 128 (no spill). Per-step body = round 13. Flat 8-way combine
// (1 barrier). prep/proj/out unchanged.
//
// ws layout (ushort elems):
//   Qf  [3i][4b][72 t][4 f][512]     @ OQ
//   Kf  [3i][4b][72 t][4 f][512]     @ OK_
//   Vf  [3i][4b][72 t][2c][2rb][512] @ OV
//   combjf [3j][4b][72 nt][12 ks][512] @ OC (+j*CSTR)  (B-frag chunks)
//   xf  [4b][72 nb][16 ks][512]      @ OXF
//   Wf  [9 s][16 ks][2 rb][512]      @ OWF
//   WoF [12 ks][8 rb][512]           @ OWOF
// Frag chunk: chunk[lane*8+e] = Op[idx=lane&31][k=8*(lane>>5)+e]

#define BB 4
#define CC 256
#define NN_ 2304
#define RR 64

#define OQ 0
#define OK_ 1769472
#define OV 3538944
#define OC 5308416
#define CSTR 1769472
#define FR_IB 147456
#define OXF 10616832
#define OWF 12976128
#define OWOF 13123584

typedef __bf16 bf16x8 __attribute__((ext_vector_type(8)));
typedef float f32x16 __attribute__((ext_vector_type(16)));
typedef unsigned short ushort8 __attribute__((ext_vector_type(8)));
typedef unsigned int uintx2 __attribute__((ext_vector_type(2)));
typedef unsigned int uintx4 __attribute__((ext_vector_type(4)));

#if __has_builtin(__builtin_amdgcn_exp2f)
#define EXP2(x) __builtin_amdgcn_exp2f(x)
#else
#define EXP2(x) exp2f(x)
#endif

__device__ __forceinline__ float bf2f(unsigned short s) {
    unsigned int u = ((unsigned int)s) << 16;
    return __builtin_bit_cast(float, u);
}
__device__ __forceinline__ unsigned int pk_bf16(float lo, float hi) {
    unsigned int r;
    asm("v_cvt_pk_bf16_f32 %0, %1, %2" : "=v"(r) : "v"(lo), "v"(hi));
    return r;
}

// ---------------------------------------------------------------------------
// Prep: bid<9 weights->A-frags; bid<12 wo->A-frags; else x->B-frags.
// ---------------------------------------------------------------------------
__global__ __launch_bounds__(256) void prep_kernel(
    const float* __restrict__ x, const float* __restrict__ wq,
    const float* __restrict__ wk, const float* __restrict__ wv,
    const float* __restrict__ wo, unsigned short* __restrict__ wsb)
{
    int bid = blockIdx.x;
    int t = threadIdx.x;
    if (bid < 9) {
        int s = bid;
        int type = s / 3, i = s % 3;
        const float* wsel = (type == 0) ? wq : (type == 1 ? wk : wv);
        const float scale = (type == 0) ? 0.18033688011112042f : 1.0f;  // 0.125*log2e
        unsigned short* dst = wsb + OWF + s * 16384;
        #pragma unroll
        for (int p = 0; p < 8; ++p) {
            int u = t + 256 * p;
            int ks = u >> 7, rb = (u >> 6) & 1, lo = u & 63;
            int row = rb * 32 + (lo & 31), c = ks * 16 + 8 * (lo >> 5);
            const float* src = wsel + ((i * 64 + row) * 256 + c);
            float4 f0 = *(const float4*)(src);
            float4 f1 = *(const float4*)(src + 4);
            uintx4 pwv = {pk_bf16(f0.x * scale, f0.y * scale),
                          pk_bf16(f0.z * scale, f0.w * scale),
                          pk_bf16(f1.x * scale, f1.y * scale),
                          pk_bf16(f1.z * scale, f1.w * scale)};
            *(uintx4*)(dst + (ks * 2 + rb) * 512 + lo * 8) = pwv;
        }
        return;
    }
    if (bid < 12) {
        int bb = bid - 9;
        #pragma unroll
        for (int p = 0; p < 8; ++p) {
            int u = t + 256 * p;
            int cg = bb * 32 + (u >> 6);
            int lane = u & 63;
            int ks = cg >> 3, rb = cg & 7;
            int row = rb * 32 + (lane & 31);
            int g = ks * 16 + 8 * (lane >> 5);
            const float* src = wo + row * 192 + g;
            float4 f0 = *(const float4*)(src);
            float4 f1 = *(const float4*)(src + 4);
            uintx4 pwv = {pk_bf16(f0.x, f0.y), pk_bf16(f0.z, f0.w),
                          pk_bf16(f1.x, f1.y), pk_bf16(f1.z, f1.w)};
            *(uintx4*)(wsb + OWOF + cg * 512 + lane * 8) = pwv;
        }
        return;
    }
    __shared__ __align__(16) float xs[64 * 132];
    int xb = bid - 12;
    int cq  = xb & 3;
    int nt2 = (xb >> 2) % 18;
    int b   = xb / 72;
    int c0 = cq * 64, n0 = nt2 * 128;
    #pragma unroll
    for (int p = 0; p < 8; ++p) {
        int u = t + 256 * p;
        int cl = u >> 5, nq = (u & 31) * 4;
        *(float4*)&xs[cl * 132 + nq] =
            *(const float4*)&x[((size_t)(b * CC + c0 + cl)) * NN_ + n0 + nq];
    }
    __syncthreads();
    unsigned short* xfb = wsb + OXF + ((size_t)b) * 72 * 16 * 512;
    #pragma unroll
    for (int p = 0; p < 4; ++p) {
        int u = t + 256 * p;
        int nb_l = u >> 8, ks_l = (u >> 6) & 3, lo = u & 63;
        int hh = lo >> 5, idx = lo & 31;
        int clb = ks_l * 16 + 8 * hh;
        int nn = nb_l * 32 + idx;
        unsigned int pw[4];
        #pragma unroll
        for (int d = 0; d < 4; ++d) {
            float a  = xs[(clb + 2 * d) * 132 + nn];
            float bb2 = xs[(clb + 2 * d + 1) * 132 + nn];
            pw[d] = pk_bf16(a, bb2);
        }
        int nb = nt2 * 4 + nb_l, ks = cq * 4 + ks_l;
        *(uintx4*)(xfb + (nb * 16 + ks) * 512 + lo * 8) =
            (uintx4){pw[0], pw[1], pw[2], pw[3]};
    }
}

// ---------------------------------------------------------------------------
// Kernel: MFMA projection (unchanged structure).
// ---------------------------------------------------------------------------
__global__ __launch_bounds__(256) void proj_mfma(unsigned short* __restrict__ wsb)
{
    int bid = blockIdx.x;
    int s = bid / 72;
    int rem = bid % 72;
    int b = rem / 18, nb4 = rem % 18;
    int type = s / 3, i = s % 3;
    int t = threadIdx.x;
    int w = t >> 6, lane = t & 63;
    int lq = lane & 31, h = lane >> 5;
    int nb = nb4 * 4 + w;

    const unsigned short* wf = wsb + OWF + s * 16384 + lane * 8;
    const unsigned short* xf = wsb + OXF + ((size_t)(b * 72 + nb) * 16) * 512 + lane * 8;

    f32x16 o0 = {}, o1 = {};
    if (type < 2) {
        #pragma unroll
        for (int ks = 0; ks < 16; ++ks) {
            bf16x8 a0 = *(const bf16x8*)(wf + ks * 1024);
            bf16x8 a1 = *(const bf16x8*)(wf + ks * 1024 + 512);
            bf16x8 bx = *(const bf16x8*)(xf + ks * 512);
            o0 = __builtin_amdgcn_mfma_f32_32x32x16_bf16(a0, bx, o0, 0, 0, 0);
            o1 = __builtin_amdgcn_mfma_f32_32x32x16_bf16(a1, bx, o1, 0, 0, 0);
        }
    } else {
        #pragma unroll
        for (int ks = 0; ks < 16; ++ks) {
            bf16x8 a0 = *(const bf16x8*)(wf + ks * 1024);
            bf16x8 a1 = *(const bf16x8*)(wf + ks * 1024 + 512);
            bf16x8 bx = *(const bf16x8*)(xf + ks * 512);
            o0 = __builtin_amdgcn_mfma_f32_32x32x16_bf16(bx, a0, o0, 0, 0, 0);
            o1 = __builtin_amdgcn_mfma_f32_32x32x16_bf16(bx, a1, o1, 0, 0, 0);
        }
    }

    unsigned short* dstbase =
        wsb + ((type == 0) ? OQ : (type == 1 ? OK_ : OV)) +
        ((size_t)(i * 4 + b)) * FR_IB + nb * 2048;

    if (type < 2) {
        #pragma unroll
        for (int g = 0; g < 4; ++g) {
            int kd = 8 * g + 4 * h;
            int off = (kd >> 4) * 512 + ((kd >> 3) & 1) * 256 + lq * 8 + (kd & 7);
            *(uintx2*)(dstbase + off) =
                (uintx2){pk_bf16(o0[4 * g], o0[4 * g + 1]),
                         pk_bf16(o0[4 * g + 2], o0[4 * g + 3])};
            int kd2 = kd + 32;
            int off2 = (kd2 >> 4) * 512 + ((kd2 >> 3) & 1) * 256 + lq * 8 + (kd2 & 7);
            *(uintx2*)(dstbase + off2) =
                (uintx2){pk_bf16(o1[4 * g], o1[4 * g + 1]),
                         pk_bf16(o1[4 * g + 2], o1[4 * g + 3])};
        }
    } else {
        #pragma unroll
        for (int g = 0; g < 4; ++g) {
            int off = (g >> 1) * 1024 + (g & 1) * 256 + lq * 8 + 4 * h;
            *(uintx2*)(dstbase + off) =
                (uintx2){pk_bf16(o0[4 * g], o0[4 * g + 1]),
                         pk_bf16(o0[4 * g + 2], o0[4 * g + 3])};
            *(uintx2*)(dstbase + off + 512) =
                (uintx2){pk_bf16(o1[4 * g], o1[4 * g + 1]),
                         pk_bf16(o1[4 * g + 2], o1[4 * g + 3])};
        }
    }
}

// ---------------------------------------------------------------------------
// Kernel: barrier-free MFMA flash attention, 8-way key-split.
// Block = 8 waves (512 thr), one (i,j,b,32-q tile); wave w streams keys
// [w*288, w*288+288) = 9 x 32-key steps direct from global. Round-13 step
// body (single K set reload-after-use, V JIT, VALU l-tree). Combine: waves
// 1-7 post (O,l) to LDS [lane][36]; 1 barrier; wave 0 reduces + stores.
// ---------------------------------------------------------------------------
__global__ __launch_bounds__(512, 4) void attn_kernel(unsigned short* __restrict__ wsb)
{
    __shared__ __align__(16) float fl[7 * 2304];   // 64.5KB -> 2 blocks/CU

    int bid = blockIdx.x;
    int wid = (bid & 7) * 324 + (bid >> 3);   // XCD-bijective (2592 = 8*324)
    int s12 = wid / 216;                      // (j,b) reuse set
    int rem = wid % 216;
    int j = s12 >> 2, b = s12 & 3;
    int i = rem / 72;
    int qp = rem % 72;
    int w = threadIdx.x >> 6;                 // wave = key-slice 0..7
    int lane = threadIdx.x & 63;
    int lq = lane & 31;
    int h = lane >> 5;
    int q0 = qp * 32;

    const unsigned short* qtf = wsb + OQ + ((size_t)(i * 4 + b)) * FR_IB +
                                qp * 2048 + lane * 8;
    const unsigned short* kp = wsb + OK_ + ((size_t)(j * 4 + b)) * FR_IB +
                               (size_t)(w * 9) * 2048 + lane * 8;
    const unsigned short* vp = wsb + OV + ((size_t)(j * 4 + b)) * FR_IB +
                               (size_t)(w * 9) * 2048 + lane * 8;

    bf16x8 bq0 = *(const bf16x8*)(qtf + 0);
    bf16x8 bq1 = *(const bf16x8*)(qtf + 512);
    bf16x8 bq2 = *(const bf16x8*)(qtf + 1024);
    bf16x8 bq3 = *(const bf16x8*)(qtf + 1536);

    f32x16 o0 = {}, o1 = {};
    float l_loc = 0.f;

    // preload K for local step 0
    bf16x8 k0 = *(const bf16x8*)(kp + 0 * 512);
    bf16x8 k1 = *(const bf16x8*)(kp + 1 * 512);
    bf16x8 k2 = *(const bf16x8*)(kp + 2 * 512);
    bf16x8 k3 = *(const bf16x8*)(kp + 3 * 512);

    for (int step = 0; step < 9; ++step) {
        // V just-in-time: lands under QK+exp
        const unsigned short* vb = vp + (size_t)step * 2048;
        bf16x8 v00 = *(const bf16x8*)(vb + 0 * 512);  // c0,rb0
        bf16x8 v10 = *(const bf16x8*)(vb + 1 * 512);  // c0,rb1
        bf16x8 v01 = *(const bf16x8*)(vb + 2 * 512);  // c1,rb0
        bf16x8 v11 = *(const bf16x8*)(vb + 3 * 512);  // c1,rb1

        f32x16 s = {};
        s = __builtin_amdgcn_mfma_f32_32x32x16_bf16(k0, bq0, s, 0, 0, 0);
        s = __builtin_amdgcn_mfma_f32_32x32x16_bf16(k1, bq1, s, 0, 0, 0);
        s = __builtin_amdgcn_mfma_f32_32x32x16_bf16(k2, bq2, s, 0, 0, 0);
        s = __builtin_amdgcn_mfma_f32_32x32x16_bf16(k3, bq3, s, 0, 0, 0);

        // K regs dead after QK issue -> reload same regs for step+1
        {
            int nx = (step + 1 < 9) ? (step + 1) : 0;
            const unsigned short* kb = kp + (size_t)nx * 2048;
            k0 = *(const bf16x8*)(kb + 0 * 512);
            k1 = *(const bf16x8*)(kb + 1 * 512);
            k2 = *(const bf16x8*)(kb + 2 * 512);
            k3 = *(const bf16x8*)(kb + 3 * 512);
        }

        // raw v_exp_f32 — inputs bounded (|S|log2e <= ~12)
        #pragma unroll
        for (int r = 0; r < 16; ++r) s[r] = EXP2(s[r]);
        l_loc += ((s[0] + s[1]) + (s[2] + s[3])) + ((s[4] + s[5]) + (s[6] + s[7])) +
                 ((s[8] + s[9]) + (s[10] + s[11])) + ((s[12] + s[13]) + (s[14] + s[15]));

        {   // keys 0..15
            unsigned int a0 = pk_bf16(s[0], s[1]);
            unsigned int a1 = pk_bf16(s[2], s[3]);
            unsigned int b0 = pk_bf16(s[4], s[5]);
            unsigned int b1 = pk_bf16(s[6], s[7]);
            uintx2 r0 = __builtin_amdgcn_permlane32_swap(a0, b0, false, false);
            uintx2 r1 = __builtin_amdgcn_permlane32_swap(a1, b1, false, false);
            uintx4 pwv = {r0[0], r1[0], r0[1], r1[1]};
            bf16x8 pa = __builtin_bit_cast(bf16x8, pwv);
            o0 = __builtin_amdgcn_mfma_f32_32x32x16_bf16(v00, pa, o0, 0, 0, 0);
            o1 = __builtin_amdgcn_mfma_f32_32x32x16_bf16(v10, pa, o1, 0, 0, 0);
        }
        {   // keys 16..31
            unsigned int a0 = pk_bf16(s[8], s[9]);
            unsigned int a1 = pk_bf16(s[10], s[11]);
            unsigned int b0 = pk_bf16(s[12], s[13]);
            unsigned int b1 = pk_bf16(s[14], s[15]);
            uintx2 r0 = __builtin_amdgcn_permlane32_swap(a0, b0, false, false);
            uintx2 r1 = __builtin_amdgcn_permlane32_swap(a1, b1, false, false);
            uintx4 pwv = {r0[0], r1[0], r0[1], r1[1]};
            bf16x8 pa = __builtin_bit_cast(bf16x8, pwv);
            o0 = __builtin_amdgcn_mfma_f32_32x32x16_bf16(v01, pa, o0, 0, 0, 0);
            o1 = __builtin_amdgcn_mfma_f32_32x32x16_bf16(v11, pa, o1, 0, 0, 0);
        }
    }

    // per-wave l (both halves of this wave's 288 keys)
    float l_full = l_loc + __shfl_xor(l_loc, 32);

    // ---- flat 8-way combine: O = sum O_k / sum l_k (exact, no-max) ----
    if (w > 0) {
        float* sl = fl + (w - 1) * 2304 + lane * 36;
        #pragma unroll
        for (int g = 0; g < 4; ++g) {
            *(float4*)(sl + 4 * g) =
                make_float4(o0[4 * g], o0[4 * g + 1], o0[4 * g + 2], o0[4 * g + 3]);
            *(float4*)(sl + 16 + 4 * g) =
                make_float4(o1[4 * g], o1[4 * g + 1], o1[4 * g + 2], o1[4 * g + 3]);
        }
        sl[32] = l_full;
    }
    __syncthreads();
    if (w > 0) return;

    #pragma unroll
    for (int sidx = 0; sidx < 7; ++sidx) {
        const float* sl = fl + sidx * 2304 + lane * 36;
        #pragma unroll
        for (int g = 0; g < 4; ++g) {
            float4 a = *(const float4*)(sl + 4 * g);
            float4 bb2 = *(const float4*)(sl + 16 + 4 * g);
            o0[4 * g] += a.x; o0[4 * g + 1] += a.y;
            o0[4 * g + 2] += a.z; o0[4 * g + 3] += a.w;
            o1[4 * g] += bb2.x; o1[4 * g + 1] += bb2.y;
            o1[4 * g + 2] += bb2.z; o1[4 * g + 3] += bb2.w;
        }
        l_full += sl[32];
    }

    float inv = 1.f / l_full;
    o0 *= inv; o1 *= inv;

    // transpose O^T -> per-query rows (wave-0-local LDS reuse), write comb frags
    float* tw = fl;
    #pragma unroll
    for (int reg = 0; reg < 16; ++reg) {
        int rv = (reg & 3) + 8 * (reg >> 2) + 4 * h;
        tw[lq * 65 + rv] = o0[reg];
        tw[lq * 65 + 32 + rv] = o1[reg];
    }
    // chunk[lane*8+e] = comb[n=q0+(lane&31)][g = i*64 + ksl*16 + 8h + e]
    unsigned short* cb = wsb + OC + (size_t)j * CSTR +
                         ((size_t)((b * 72 + qp) * 12 + i * 4)) * 512;
    #pragma unroll
    for (int ksl = 0; ksl < 4; ++ksl) {
        const float* src = tw + lq * 65 + ksl * 16 + 8 * h;
        uintx4 pwv = {pk_bf16(src[0], src[1]), pk_bf16(src[2], src[3]),
                      pk_bf16(src[4], src[5]), pk_bf16(src[6], src[7])};
        *(uintx4*)(cb + ksl * 512 + lane * 8) = pwv;
    }
}

// ---------------------------------------------------------------------------
// Kernel: MFMA out-projection + sigmoid gate.
// ---------------------------------------------------------------------------
__global__ __launch_bounds__(256) void out_mfma(
    const float* __restrict__ x, const unsigned short* __restrict__ wsb,
    float* __restrict__ out)
{
    int bid = blockIdx.x;
    int ch = bid & 1;
    int nt = (bid >> 1) % 72;
    int b  = bid / 144;
    int n0 = nt * 32;
    int t = threadIdx.x;
    int w = t >> 6, lane = t & 63;
    int lq = lane & 31, h = lane >> 5;
    int rb = ch * 4 + w;

    const unsigned short* wof = wsb + OWOF + lane * 8;
    const unsigned short* cbase = wsb + OC +
        ((size_t)((b * 72 + nt) * 12)) * 512 + lane * 8;

    f32x16 acc = {};
    #pragma unroll
    for (int j = 0; j < 3; ++j) {
        const unsigned short* cj = cbase + (size_t)j * CSTR;
        #pragma unroll
        for (int ksx = 0; ksx < 12; ++ksx) {
            bf16x8 bx = *(const bf16x8*)(cj + ksx * 512);
            bf16x8 a0 = *(const bf16x8*)(wof + (ksx * 8 + rb) * 512);
            acc = __builtin_amdgcn_mfma_f32_32x32x16_bf16(a0, bx, acc, 0, 0, 0);
        }
    }

    int c0 = rb * 32;
    #pragma unroll
    for (int reg = 0; reg < 16; ++reg) {
        int c = c0 + (reg & 3) + 8 * (reg >> 2) + 4 * h;
        size_t idx = ((size_t)(b * CC + c)) * NN_ + n0 + lq;
        float sg = 1.f / (1.f + EXP2(acc[reg] * -1.44269504f));
        out[idx] = x[idx] * sg;
    }
}

extern "C" void kernel_launch(void* const* d_in, const int* in_sizes, int n_in,
                              void* d_out, int out_size, void* d_ws, size_t ws_size,
                              hipStream_t stream) {
    const float* x  = (const float*)d_in[0];
    const float* wq = (const float*)d_in[1];
    const float* wk = (const float*)d_in[2];
    const float* wv = (const float*)d_in[3];
    const float* wo = (const float*)d_in[4];
    unsigned short* wsb = (unsigned short*)d_ws;
    float* out = (float*)d_out;

    prep_kernel<<<300, 256, 0, stream>>>(x, wq, wk, wv, wo, wsb);
    proj_mfma<<<648, 256, 0, stream>>>(wsb);
    attn_kernel<<<2592, 512, 0, stream>>>(wsb);
    out_mfma<<<576, 256, 0, stream>>>(x, wsb, out);
}

// Round 15
// 96.679 us; speedup vs baseline: 1.0216x; 1.0069x over previous
//
#include <hip/hip_runtime.h>

// NestedAttention MI355X round 15: round-12 base + ONE change — V-frag loads
// moved from step-top (JIT, ~150cyc lead) to end of previous step's PV
// (reload-in-place, full-step lead), mirroring the proven K pattern.
// Everything else identical to round 12 (best attn: 72.1 us).
//
// ws layout (ushort elems):
//   Qf  [3i][4b][72 t][4 f][512]     @ OQ
//   Kf  [3i][4b][72 t][4 f][512]     @ OK_
//   Vf  [3i][4b][72 t][2c][2rb][512] @ OV
//   combjf [3j][4b][72 nt][12 ks][512] @ OC (+j*CSTR)  (B-frag chunks)
//   xf  [4b][72 nb][16 ks][512]      @ OXF
//   Wf  [9 s][16 ks][2 rb][512]      @ OWF
//   WoF [12 ks][8 rb][512]           @ OWOF
// Frag chunk: chunk[lane*8+e] = Op[idx=lane&31][k=8*(lane>>5)+e]

#define BB 4
#define CC 256
#define NN_ 2304
#define RR 64

#define OQ 0
#define OK_ 1769472
#define OV 3538944
#define OC 5308416
#define CSTR 1769472
#define FR_IB 147456
#define OXF 10616832
#define OWF 12976128
#define OWOF 13123584

typedef __bf16 bf16x8 __attribute__((ext_vector_type(8)));
typedef float f32x16 __attribute__((ext_vector_type(16)));
typedef unsigned short ushort8 __attribute__((ext_vector_type(8)));
typedef unsigned int uintx2 __attribute__((ext_vector_type(2)));
typedef unsigned int uintx4 __attribute__((ext_vector_type(4)));

#if __has_builtin(__builtin_amdgcn_exp2f)
#define EXP2(x) __builtin_amdgcn_exp2f(x)
#else
#define EXP2(x) exp2f(x)
#endif

__device__ __forceinline__ float bf2f(unsigned short s) {
    unsigned int u = ((unsigned int)s) << 16;
    return __builtin_bit_cast(float, u);
}
__device__ __forceinline__ unsigned int pk_bf16(float lo, float hi) {
    unsigned int r;
    asm("v_cvt_pk_bf16_f32 %0, %1, %2" : "=v"(r) : "v"(lo), "v"(hi));
    return r;
}

// ---------------------------------------------------------------------------
// Prep: bid<9 weights->A-frags; bid<12 wo->A-frags; else x->B-frags.
// ---------------------------------------------------------------------------
__global__ __launch_bounds__(256) void prep_kernel(
    const float* __restrict__ x, const float* __restrict__ wq,
    const float* __restrict__ wk, const float* __restrict__ wv,
    const float* __restrict__ wo, unsigned short* __restrict__ wsb)
{
    int bid = blockIdx.x;
    int t = threadIdx.x;
    if (bid < 9) {
        int s = bid;
        int type = s / 3, i = s % 3;
        const float* wsel = (type == 0) ? wq : (type == 1 ? wk : wv);
        const float scale = (type == 0) ? 0.18033688011112042f : 1.0f;  // 0.125*log2e
        unsigned short* dst = wsb + OWF + s * 16384;
        #pragma unroll
        for (int p = 0; p < 8; ++p) {
            int u = t + 256 * p;
            int ks = u >> 7, rb = (u >> 6) & 1, lo = u & 63;
            int row = rb * 32 + (lo & 31), c = ks * 16 + 8 * (lo >> 5);
            const float* src = wsel + ((i * 64 + row) * 256 + c);
            float4 f0 = *(const float4*)(src);
            float4 f1 = *(const float4*)(src + 4);
            uintx4 pwv = {pk_bf16(f0.x * scale, f0.y * scale),
                          pk_bf16(f0.z * scale, f0.w * scale),
                          pk_bf16(f1.x * scale, f1.y * scale),
                          pk_bf16(f1.z * scale, f1.w * scale)};
            *(uintx4*)(dst + (ks * 2 + rb) * 512 + lo * 8) = pwv;
        }
        return;
    }
    if (bid < 12) {
        int bb = bid - 9;
        #pragma unroll
        for (int p = 0; p < 8; ++p) {
            int u = t + 256 * p;
            int cg = bb * 32 + (u >> 6);
            int lane = u & 63;
            int ks = cg >> 3, rb = cg & 7;
            int row = rb * 32 + (lane & 31);
            int g = ks * 16 + 8 * (lane >> 5);
            const float* src = wo + row * 192 + g;
            float4 f0 = *(const float4*)(src);
            float4 f1 = *(const float4*)(src + 4);
            uintx4 pwv = {pk_bf16(f0.x, f0.y), pk_bf16(f0.z, f0.w),
                          pk_bf16(f1.x, f1.y), pk_bf16(f1.z, f1.w)};
            *(uintx4*)(wsb + OWOF + cg * 512 + lane * 8) = pwv;
        }
        return;
    }
    __shared__ __align__(16) float xs[64 * 132];
    int xb = bid - 12;
    int cq  = xb & 3;
    int nt2 = (xb >> 2) % 18;
    int b   = xb / 72;
    int c0 = cq * 64, n0 = nt2 * 128;
    #pragma unroll
    for (int p = 0; p < 8; ++p) {
        int u = t + 256 * p;
        int cl = u >> 5, nq = (u & 31) * 4;
        *(float4*)&xs[cl * 132 + nq] =
            *(const float4*)&x[((size_t)(b * CC + c0 + cl)) * NN_ + n0 + nq];
    }
    __syncthreads();
    unsigned short* xfb = wsb + OXF + ((size_t)b) * 72 * 16 * 512;
    #pragma unroll
    for (int p = 0; p < 4; ++p) {
        int u = t + 256 * p;
        int nb_l = u >> 8, ks_l = (u >> 6) & 3, lo = u & 63;
        int hh = lo >> 5, idx = lo & 31;
        int clb = ks_l * 16 + 8 * hh;
        int nn = nb_l * 32 + idx;
        unsigned int pw[4];
        #pragma unroll
        for (int d = 0; d < 4; ++d) {
            float a  = xs[(clb + 2 * d) * 132 + nn];
            float bb2 = xs[(clb + 2 * d + 1) * 132 + nn];
            pw[d] = pk_bf16(a, bb2);
        }
        int nb = nt2 * 4 + nb_l, ks = cq * 4 + ks_l;
        *(uintx4*)(xfb + (nb * 16 + ks) * 512 + lo * 8) =
            (uintx4){pw[0], pw[1], pw[2], pw[3]};
    }
}

// ---------------------------------------------------------------------------
// Kernel: MFMA projection (unchanged structure).
// ---------------------------------------------------------------------------
__global__ __launch_bounds__(256) void proj_mfma(unsigned short* __restrict__ wsb)
{
    int bid = blockIdx.x;
    int s = bid / 72;
    int rem = bid % 72;
    int b = rem / 18, nb4 = rem % 18;
    int type = s / 3, i = s % 3;
    int t = threadIdx.x;
    int w = t >> 6, lane = t & 63;
    int lq = lane & 31, h = lane >> 5;
    int nb = nb4 * 4 + w;

    const unsigned short* wf = wsb + OWF + s * 16384 + lane * 8;
    const unsigned short* xf = wsb + OXF + ((size_t)(b * 72 + nb) * 16) * 512 + lane * 8;

    f32x16 o0 = {}, o1 = {};
    if (type < 2) {
        #pragma unroll
        for (int ks = 0; ks < 16; ++ks) {
            bf16x8 a0 = *(const bf16x8*)(wf + ks * 1024);
            bf16x8 a1 = *(const bf16x8*)(wf + ks * 1024 + 512);
            bf16x8 bx = *(const bf16x8*)(xf + ks * 512);
            o0 = __builtin_amdgcn_mfma_f32_32x32x16_bf16(a0, bx, o0, 0, 0, 0);
            o1 = __builtin_amdgcn_mfma_f32_32x32x16_bf16(a1, bx, o1, 0, 0, 0);
        }
    } else {
        #pragma unroll
        for (int ks = 0; ks < 16; ++ks) {
            bf16x8 a0 = *(const bf16x8*)(wf + ks * 1024);
            bf16x8 a1 = *(const bf16x8*)(wf + ks * 1024 + 512);
            bf16x8 bx = *(const bf16x8*)(xf + ks * 512);
            o0 = __builtin_amdgcn_mfma_f32_32x32x16_bf16(bx, a0, o0, 0, 0, 0);
            o1 = __builtin_amdgcn_mfma_f32_32x32x16_bf16(bx, a1, o1, 0, 0, 0);
        }
    }

    unsigned short* dstbase =
        wsb + ((type == 0) ? OQ : (type == 1 ? OK_ : OV)) +
        ((size_t)(i * 4 + b)) * FR_IB + nb * 2048;

    if (type < 2) {
        #pragma unroll
        for (int g = 0; g < 4; ++g) {
            int kd = 8 * g + 4 * h;
            int off = (kd >> 4) * 512 + ((kd >> 3) & 1) * 256 + lq * 8 + (kd & 7);
            *(uintx2*)(dstbase + off) =
                (uintx2){pk_bf16(o0[4 * g], o0[4 * g + 1]),
                         pk_bf16(o0[4 * g + 2], o0[4 * g + 3])};
            int kd2 = kd + 32;
            int off2 = (kd2 >> 4) * 512 + ((kd2 >> 3) & 1) * 256 + lq * 8 + (kd2 & 7);
            *(uintx2*)(dstbase + off2) =
                (uintx2){pk_bf16(o1[4 * g], o1[4 * g + 1]),
                         pk_bf16(o1[4 * g + 2], o1[4 * g + 3])};
        }
    } else {
        #pragma unroll
        for (int g = 0; g < 4; ++g) {
            int off = (g >> 1) * 1024 + (g & 1) * 256 + lq * 8 + 4 * h;
            *(uintx2*)(dstbase + off) =
                (uintx2){pk_bf16(o0[4 * g], o0[4 * g + 1]),
                         pk_bf16(o0[4 * g + 2], o0[4 * g + 3])};
            *(uintx2*)(dstbase + off + 512) =
                (uintx2){pk_bf16(o1[4 * g], o1[4 * g + 1]),
                         pk_bf16(o1[4 * g + 2], o1[4 * g + 3])};
        }
    }
}

// ---------------------------------------------------------------------------
// Kernel: barrier-free MFMA flash attention (round-12 structure).
// Block = 4 waves = 2 q-tiles x 2 key-halves. K ping-pong (sep reg sets,
// depth 1). V: reload-in-place at END of previous step's PV (full-step lead).
// l via VALU add-tree. Epilogue unchanged.
// ---------------------------------------------------------------------------
__global__ __launch_bounds__(256, 4) void attn_kernel(unsigned short* __restrict__ wsb)
{
    __shared__ __align__(16) float fl[4352];

    int bid = blockIdx.x;
    int wid = (bid & 7) * 162 + (bid >> 3);   // XCD-contiguous (1296 = 8*162)
    int s12 = wid / 108;
    int rem = wid % 108;
    int j = s12 >> 2, b = s12 & 3;
    int i = rem / 36;
    int qp = rem % 36;
    int w = threadIdx.x >> 6;
    int ks = w & 1, qloc = w >> 1;
    int lane = threadIdx.x & 63;
    int lq = lane & 31;
    int h = lane >> 5;
    int q0 = (qp * 2 + qloc) * 32;
    int nt = q0 >> 5;

    const unsigned short* qtf = wsb + OQ + ((size_t)(i * 4 + b)) * FR_IB +
                                nt * 2048 + lane * 8;
    const unsigned short* kp = wsb + OK_ + ((size_t)(j * 4 + b)) * FR_IB +
                               (size_t)(ks * 36) * 2048 + lane * 8;
    const unsigned short* vp = wsb + OV + ((size_t)(j * 4 + b)) * FR_IB +
                               (size_t)(ks * 36) * 2048 + lane * 8;

    bf16x8 bq0 = *(const bf16x8*)(qtf + 0);
    bf16x8 bq1 = *(const bf16x8*)(qtf + 512);
    bf16x8 bq2 = *(const bf16x8*)(qtf + 1024);
    bf16x8 bq3 = *(const bf16x8*)(qtf + 1536);

    f32x16 o0 = {}, o1 = {};
    float l_loc = 0.f;

    // loop-carried V frags (preloaded for the step about to run)
    bf16x8 v00 = *(const bf16x8*)(vp + 0 * 512);  // c0,rb0
    bf16x8 v10 = *(const bf16x8*)(vp + 1 * 512);  // c0,rb1
    bf16x8 v01 = *(const bf16x8*)(vp + 2 * 512);  // c1,rb0
    bf16x8 v11 = *(const bf16x8*)(vp + 3 * 512);  // c1,rb1

    // one 32-key step; K frags in regs, V frags in loop-carried regs.
    // After PV issues, reload V (in place) for nxt — full-step lead.
    auto compute_step = [&](bf16x8 k0, bf16x8 k1, bf16x8 k2, bf16x8 k3,
                            int nxt) {
        f32x16 s = {};
        s = __builtin_amdgcn_mfma_f32_32x32x16_bf16(k0, bq0, s, 0, 0, 0);
        s = __builtin_amdgcn_mfma_f32_32x32x16_bf16(k1, bq1, s, 0, 0, 0);
        s = __builtin_amdgcn_mfma_f32_32x32x16_bf16(k2, bq2, s, 0, 0, 0);
        s = __builtin_amdgcn_mfma_f32_32x32x16_bf16(k3, bq3, s, 0, 0, 0);

        // raw v_exp_f32 — inputs bounded (|S|log2e <= ~12)
        #pragma unroll
        for (int r = 0; r < 16; ++r) s[r] = EXP2(s[r]);
        l_loc += ((s[0] + s[1]) + (s[2] + s[3])) + ((s[4] + s[5]) + (s[6] + s[7])) +
                 ((s[8] + s[9]) + (s[10] + s[11])) + ((s[12] + s[13]) + (s[14] + s[15]));

        {   // keys 0..15
            unsigned int a0 = pk_bf16(s[0], s[1]);
            unsigned int a1 = pk_bf16(s[2], s[3]);
            unsigned int b0 = pk_bf16(s[4], s[5]);
            unsigned int b1 = pk_bf16(s[6], s[7]);
            uintx2 r0 = __builtin_amdgcn_permlane32_swap(a0, b0, false, false);
            uintx2 r1 = __builtin_amdgcn_permlane32_swap(a1, b1, false, false);
            uintx4 pwv = {r0[0], r1[0], r0[1], r1[1]};
            bf16x8 pa = __builtin_bit_cast(bf16x8, pwv);
            o0 = __builtin_amdgcn_mfma_f32_32x32x16_bf16(v00, pa, o0, 0, 0, 0);
            o1 = __builtin_amdgcn_mfma_f32_32x32x16_bf16(v10, pa, o1, 0, 0, 0);
        }
        {   // keys 16..31
            unsigned int a0 = pk_bf16(s[8], s[9]);
            unsigned int a1 = pk_bf16(s[10], s[11]);
            unsigned int b0 = pk_bf16(s[12], s[13]);
            unsigned int b1 = pk_bf16(s[14], s[15]);
            uintx2 r0 = __builtin_amdgcn_permlane32_swap(a0, b0, false, false);
            uintx2 r1 = __builtin_amdgcn_permlane32_swap(a1, b1, false, false);
            uintx4 pwv = {r0[0], r1[0], r0[1], r1[1]};
            bf16x8 pa = __builtin_bit_cast(bf16x8, pwv);
            o0 = __builtin_amdgcn_mfma_f32_32x32x16_bf16(v01, pa, o0, 0, 0, 0);
            o1 = __builtin_amdgcn_mfma_f32_32x32x16_bf16(v11, pa, o1, 0, 0, 0);
        }
        {   // reload V in place for step nxt (dead after PV issue above)
            const unsigned short* vb = vp + (size_t)nxt * 2048;
            v00 = *(const bf16x8*)(vb + 0 * 512);
            v10 = *(const bf16x8*)(vb + 1 * 512);
            v01 = *(const bf16x8*)(vb + 2 * 512);
            v11 = *(const bf16x8*)(vb + 3 * 512);
        }
    };

    // ---- K ping-pong: preload step 0 into set A ----
    bf16x8 kA0 = *(const bf16x8*)(kp + 0 * 512);
    bf16x8 kA1 = *(const bf16x8*)(kp + 1 * 512);
    bf16x8 kA2 = *(const bf16x8*)(kp + 2 * 512);
    bf16x8 kA3 = *(const bf16x8*)(kp + 3 * 512);

    for (int step = 0; step < 36; step += 2) {
        // prefetch K for step+1 into set B
        const unsigned short* kbB = kp + (size_t)(step + 1) * 2048;
        bf16x8 kB0 = *(const bf16x8*)(kbB + 0 * 512);
        bf16x8 kB1 = *(const bf16x8*)(kbB + 1 * 512);
        bf16x8 kB2 = *(const bf16x8*)(kbB + 2 * 512);
        bf16x8 kB3 = *(const bf16x8*)(kbB + 3 * 512);

        compute_step(kA0, kA1, kA2, kA3, step + 1);

        // prefetch K for step+2 into set A (wrap to 0 on last pair; unused)
        int nx = (step + 2 < 36) ? (step + 2) : 0;
        const unsigned short* kbA = kp + (size_t)nx * 2048;
        kA0 = *(const bf16x8*)(kbA + 0 * 512);
        kA1 = *(const bf16x8*)(kbA + 1 * 512);
        kA2 = *(const bf16x8*)(kbA + 2 * 512);
        kA3 = *(const bf16x8*)(kbA + 3 * 512);

        compute_step(kB0, kB1, kB2, kB3, (step + 2 < 36) ? (step + 2) : 0);
    }

    float l_full = l_loc + __shfl_xor(l_loc, 32);

    // ---- combine ks halves: O = (O0+O1)/(l0+l1) ----
    int off = qloc * 2112;
    if (ks == 1) {
        #pragma unroll
        for (int reg = 0; reg < 16; ++reg) {
            fl[off + reg * 64 + lane] = o0[reg];
            fl[off + 1024 + reg * 64 + lane] = o1[reg];
        }
        fl[off + 2048 + lane] = l_full;
    }
    __syncthreads();
    if (ks == 1) return;

    #pragma unroll
    for (int reg = 0; reg < 16; ++reg) {
        o0[reg] += fl[off + reg * 64 + lane];
        o1[reg] += fl[off + 1024 + reg * 64 + lane];
    }
    float l_tot = l_full + fl[off + 2048 + lane];
    __syncthreads();   // fl reusable

    float inv = 1.f / l_tot;
    o0 *= inv; o1 *= inv;

    // transpose O^T -> per-query rows, then write comb as B-frag chunks
    float* tw = fl + qloc * 2080;
    #pragma unroll
    for (int reg = 0; reg < 16; ++reg) {
        int rv = (reg & 3) + 8 * (reg >> 2) + 4 * h;
        tw[lq * 65 + rv] = o0[reg];
        tw[lq * 65 + 32 + rv] = o1[reg];
    }
    // chunk[lane*8+e] = comb[n=q0+(lane&31)][g = i*64 + ksl*16 + 8h + e]
    unsigned short* cb = wsb + OC + (size_t)j * CSTR +
                         ((size_t)((b * 72 + nt) * 12 + i * 4)) * 512;
    #pragma unroll
    for (int ksl = 0; ksl < 4; ++ksl) {
        const float* src = tw + lq * 65 + ksl * 16 + 8 * h;
        uintx4 pwv = {pk_bf16(src[0], src[1]), pk_bf16(src[2], src[3]),
                      pk_bf16(src[4], src[5]), pk_bf16(src[6], src[7])};
        *(uintx4*)(cb + ksl * 512 + lane * 8) = pwv;
    }
}

// ---------------------------------------------------------------------------
// Kernel: MFMA out-projection + sigmoid gate.
// ---------------------------------------------------------------------------
__global__ __launch_bounds__(256) void out_mfma(
    const float* __restrict__ x, const unsigned short* __restrict__ wsb,
    float* __restrict__ out)
{
    int bid = blockIdx.x;
    int ch = bid & 1;
    int nt = (bid >> 1) % 72;
    int b  = bid / 144;
    int n0 = nt * 32;
    int t = threadIdx.x;
    int w = t >> 6, lane = t & 63;
    int lq = lane & 31, h = lane >> 5;
    int rb = ch * 4 + w;

    const unsigned short* wof = wsb + OWOF + lane * 8;
    const unsigned short* cbase = wsb + OC +
        ((size_t)((b * 72 + nt) * 12)) * 512 + lane * 8;

    f32x16 acc = {};
    #pragma unroll
    for (int j = 0; j < 3; ++j) {
        const unsigned short* cj = cbase + (size_t)j * CSTR;
        #pragma unroll
        for (int ksx = 0; ksx < 12; ++ksx) {
            bf16x8 bx = *(const bf16x8*)(cj + ksx * 512);
            bf16x8 a0 = *(const bf16x8*)(wof + (ksx * 8 + rb) * 512);
            acc = __builtin_amdgcn_mfma_f32_32x32x16_bf16(a0, bx, acc, 0, 0, 0);
        }
    }

    int c0 = rb * 32;
    #pragma unroll
    for (int reg = 0; reg < 16; ++reg) {
        int c = c0 + (reg & 3) + 8 * (reg >> 2) + 4 * h;
        size_t idx = ((size_t)(b * CC + c)) * NN_ + n0 + lq;
        float sg = 1.f / (1.f + EXP2(acc[reg] * -1.44269504f));
        out[idx] = x[idx] * sg;
    }
}

extern "C" void kernel_launch(void* const* d_in, const int* in_sizes, int n_in,
                              void* d_out, int out_size, void* d_ws, size_t ws_size,
                              hipStream_t stream) {
    const float* x  = (const float*)d_in[0];
    const float* wq = (const float*)d_in[1];
    const float* wk = (const float*)d_in[2];
    const float* wv = (const float*)d_in[3];
    const float* wo = (const float*)d_in[4];
    unsigned short* wsb = (unsigned short*)d_ws;
    float* out = (float*)d_out;

    prep_kernel<<<300, 256, 0, stream>>>(x, wq, wk, wv, wo, wsb);
    proj_mfma<<<648, 256, 0, stream>>>(wsb);
    attn_kernel<<<1296, 256, 0, stream>>>(wsb);
    out_mfma<<<576, 256, 0, stream>>>(x, wsb, out);
}

// Round 16
// 96.149 us; speedup vs baseline: 1.0272x; 1.0055x over previous
//
#include <hip/hip_runtime.h>

// NestedAttention MI355X round 16: max-residency attn. 4-way key-split,
// 2592 x 4-wave blocks (1 q-tile x 4 key-quarters, 18 steps), LDS 16.9KB
// (2-slot tree combine) -> 8 blocks/CU = 32 waves/CU supply at VGPR 64.
// Step body = round 12 verbatim (K ping-pong, V JIT, VALU l-tree).
//
// ws layout (ushort elems):
//   Qf  [3i][4b][72 t][4 f][512]     @ OQ
//   Kf  [3i][4b][72 t][4 f][512]     @ OK_
//   Vf  [3i][4b][72 t][2c][2rb][512] @ OV
//   combjf [3j][4b][72 nt][12 ks][512] @ OC (+j*CSTR)  (B-frag chunks)
//   xf  [4b][72 nb][16 ks][512]      @ OXF
//   Wf  [9 s][16 ks][2 rb][512]      @ OWF
//   WoF [12 ks][8 rb][512]           @ OWOF
// Frag chunk: chunk[lane*8+e] = Op[idx=lane&31][k=8*(lane>>5)+e]

#define BB 4
#define CC 256
#define NN_ 2304
#define RR 64

#define OQ 0
#define OK_ 1769472
#define OV 3538944
#define OC 5308416
#define CSTR 1769472
#define FR_IB 147456
#define OXF 10616832
#define OWF 12976128
#define OWOF 13123584

typedef __bf16 bf16x8 __attribute__((ext_vector_type(8)));
typedef float f32x16 __attribute__((ext_vector_type(16)));
typedef unsigned short ushort8 __attribute__((ext_vector_type(8)));
typedef unsigned int uintx2 __attribute__((ext_vector_type(2)));
typedef unsigned int uintx4 __attribute__((ext_vector_type(4)));

#if __has_builtin(__builtin_amdgcn_exp2f)
#define EXP2(x) __builtin_amdgcn_exp2f(x)
#else
#define EXP2(x) exp2f(x)
#endif

__device__ __forceinline__ float bf2f(unsigned short s) {
    unsigned int u = ((unsigned int)s) << 16;
    return __builtin_bit_cast(float, u);
}
__device__ __forceinline__ unsigned int pk_bf16(float lo, float hi) {
    unsigned int r;
    asm("v_cvt_pk_bf16_f32 %0, %1, %2" : "=v"(r) : "v"(lo), "v"(hi));
    return r;
}

// ---------------------------------------------------------------------------
// Prep: bid<9 weights->A-frags; bid<12 wo->A-frags; else x->B-frags.
// ---------------------------------------------------------------------------
__global__ __launch_bounds__(256) void prep_kernel(
    const float* __restrict__ x, const float* __restrict__ wq,
    const float* __restrict__ wk, const float* __restrict__ wv,
    const float* __restrict__ wo, unsigned short* __restrict__ wsb)
{
    int bid = blockIdx.x;
    int t = threadIdx.x;
    if (bid < 9) {
        int s = bid;
        int type = s / 3, i = s % 3;
        const float* wsel = (type == 0) ? wq : (type == 1 ? wk : wv);
        const float scale = (type == 0) ? 0.18033688011112042f : 1.0f;  // 0.125*log2e
        unsigned short* dst = wsb + OWF + s * 16384;
        #pragma unroll
        for (int p = 0; p < 8; ++p) {
            int u = t + 256 * p;
            int ks = u >> 7, rb = (u >> 6) & 1, lo = u & 63;
            int row = rb * 32 + (lo & 31), c = ks * 16 + 8 * (lo >> 5);
            const float* src = wsel + ((i * 64 + row) * 256 + c);
            float4 f0 = *(const float4*)(src);
            float4 f1 = *(const float4*)(src + 4);
            uintx4 pwv = {pk_bf16(f0.x * scale, f0.y * scale),
                          pk_bf16(f0.z * scale, f0.w * scale),
                          pk_bf16(f1.x * scale, f1.y * scale),
                          pk_bf16(f1.z * scale, f1.w * scale)};
            *(uintx4*)(dst + (ks * 2 + rb) * 512 + lo * 8) = pwv;
        }
        return;
    }
    if (bid < 12) {
        int bb = bid - 9;
        #pragma unroll
        for (int p = 0; p < 8; ++p) {
            int u = t + 256 * p;
            int cg = bb * 32 + (u >> 6);
            int lane = u & 63;
            int ks = cg >> 3, rb = cg & 7;
            int row = rb * 32 + (lane & 31);
            int g = ks * 16 + 8 * (lane >> 5);
            const float* src = wo + row * 192 + g;
            float4 f0 = *(const float4*)(src);
            float4 f1 = *(const float4*)(src + 4);
            uintx4 pwv = {pk_bf16(f0.x, f0.y), pk_bf16(f0.z, f0.w),
                          pk_bf16(f1.x, f1.y), pk_bf16(f1.z, f1.w)};
            *(uintx4*)(wsb + OWOF + cg * 512 + lane * 8) = pwv;
        }
        return;
    }
    __shared__ __align__(16) float xs[64 * 132];
    int xb = bid - 12;
    int cq  = xb & 3;
    int nt2 = (xb >> 2) % 18;
    int b   = xb / 72;
    int c0 = cq * 64, n0 = nt2 * 128;
    #pragma unroll
    for (int p = 0; p < 8; ++p) {
        int u = t + 256 * p;
        int cl = u >> 5, nq = (u & 31) * 4;
        *(float4*)&xs[cl * 132 + nq] =
            *(const float4*)&x[((size_t)(b * CC + c0 + cl)) * NN_ + n0 + nq];
    }
    __syncthreads();
    unsigned short* xfb = wsb + OXF + ((size_t)b) * 72 * 16 * 512;
    #pragma unroll
    for (int p = 0; p < 4; ++p) {
        int u = t + 256 * p;
        int nb_l = u >> 8, ks_l = (u >> 6) & 3, lo = u & 63;
        int hh = lo >> 5, idx = lo & 31;
        int clb = ks_l * 16 + 8 * hh;
        int nn = nb_l * 32 + idx;
        unsigned int pw[4];
        #pragma unroll
        for (int d = 0; d < 4; ++d) {
            float a  = xs[(clb + 2 * d) * 132 + nn];
            float bb2 = xs[(clb + 2 * d + 1) * 132 + nn];
            pw[d] = pk_bf16(a, bb2);
        }
        int nb = nt2 * 4 + nb_l, ks = cq * 4 + ks_l;
        *(uintx4*)(xfb + (nb * 16 + ks) * 512 + lo * 8) =
            (uintx4){pw[0], pw[1], pw[2], pw[3]};
    }
}

// ---------------------------------------------------------------------------
// Kernel: MFMA projection (unchanged structure).
// ---------------------------------------------------------------------------
__global__ __launch_bounds__(256) void proj_mfma(unsigned short* __restrict__ wsb)
{
    int bid = blockIdx.x;
    int s = bid / 72;
    int rem = bid % 72;
    int b = rem / 18, nb4 = rem % 18;
    int type = s / 3, i = s % 3;
    int t = threadIdx.x;
    int w = t >> 6, lane = t & 63;
    int lq = lane & 31, h = lane >> 5;
    int nb = nb4 * 4 + w;

    const unsigned short* wf = wsb + OWF + s * 16384 + lane * 8;
    const unsigned short* xf = wsb + OXF + ((size_t)(b * 72 + nb) * 16) * 512 + lane * 8;

    f32x16 o0 = {}, o1 = {};
    if (type < 2) {
        #pragma unroll
        for (int ks = 0; ks < 16; ++ks) {
            bf16x8 a0 = *(const bf16x8*)(wf + ks * 1024);
            bf16x8 a1 = *(const bf16x8*)(wf + ks * 1024 + 512);
            bf16x8 bx = *(const bf16x8*)(xf + ks * 512);
            o0 = __builtin_amdgcn_mfma_f32_32x32x16_bf16(a0, bx, o0, 0, 0, 0);
            o1 = __builtin_amdgcn_mfma_f32_32x32x16_bf16(a1, bx, o1, 0, 0, 0);
        }
    } else {
        #pragma unroll
        for (int ks = 0; ks < 16; ++ks) {
            bf16x8 a0 = *(const bf16x8*)(wf + ks * 1024);
            bf16x8 a1 = *(const bf16x8*)(wf + ks * 1024 + 512);
            bf16x8 bx = *(const bf16x8*)(xf + ks * 512);
            o0 = __builtin_amdgcn_mfma_f32_32x32x16_bf16(bx, a0, o0, 0, 0, 0);
            o1 = __builtin_amdgcn_mfma_f32_32x32x16_bf16(bx, a1, o1, 0, 0, 0);
        }
    }

    unsigned short* dstbase =
        wsb + ((type == 0) ? OQ : (type == 1 ? OK_ : OV)) +
        ((size_t)(i * 4 + b)) * FR_IB + nb * 2048;

    if (type < 2) {
        #pragma unroll
        for (int g = 0; g < 4; ++g) {
            int kd = 8 * g + 4 * h;
            int off = (kd >> 4) * 512 + ((kd >> 3) & 1) * 256 + lq * 8 + (kd & 7);
            *(uintx2*)(dstbase + off) =
                (uintx2){pk_bf16(o0[4 * g], o0[4 * g + 1]),
                         pk_bf16(o0[4 * g + 2], o0[4 * g + 3])};
            int kd2 = kd + 32;
            int off2 = (kd2 >> 4) * 512 + ((kd2 >> 3) & 1) * 256 + lq * 8 + (kd2 & 7);
            *(uintx2*)(dstbase + off2) =
                (uintx2){pk_bf16(o1[4 * g], o1[4 * g + 1]),
                         pk_bf16(o1[4 * g + 2], o1[4 * g + 3])};
        }
    } else {
        #pragma unroll
        for (int g = 0; g < 4; ++g) {
            int off = (g >> 1) * 1024 + (g & 1) * 256 + lq * 8 + 4 * h;
            *(uintx2*)(dstbase + off) =
                (uintx2){pk_bf16(o0[4 * g], o0[4 * g + 1]),
                         pk_bf16(o0[4 * g + 2], o0[4 * g + 3])};
            *(uintx2*)(dstbase + off + 512) =
                (uintx2){pk_bf16(o1[4 * g], o1[4 * g + 1]),
                         pk_bf16(o1[4 * g + 2], o1[4 * g + 3])};
        }
    }
}

// ---------------------------------------------------------------------------
// Kernel: barrier-free MFMA flash attention, 4-way key-split, max residency.
// Block = 4 waves = one 32-q tile; wave w streams keys [w*576, w*576+576)
// (18 x 32-key steps) direct from global. Round-12 step body. Combine:
// 2-slot LDS tree (w1,w3 post; w0,w2 add; w2 posts; w0 adds) — fp32 exact.
// ---------------------------------------------------------------------------
__global__ __launch_bounds__(256, 4) void attn_kernel(unsigned short* __restrict__ wsb)
{
    __shared__ __align__(16) float fl[4224];  // 2 slots x 2112 = 16.9KB

    int bid = blockIdx.x;
    int wid = (bid & 7) * 324 + (bid >> 3);   // XCD-bijective (2592 = 8*324)
    int s12 = wid / 216;                      // (j,b) reuse set
    int rem = wid % 216;
    int j = s12 >> 2, b = s12 & 3;
    int i = rem / 72;
    int qp = rem % 72;
    int w = threadIdx.x >> 6;                 // key-quarter 0..3
    int lane = threadIdx.x & 63;
    int lq = lane & 31;
    int h = lane >> 5;
    int q0 = qp * 32;

    const unsigned short* qtf = wsb + OQ + ((size_t)(i * 4 + b)) * FR_IB +
                                qp * 2048 + lane * 8;
    const unsigned short* kp = wsb + OK_ + ((size_t)(j * 4 + b)) * FR_IB +
                               (size_t)(w * 18) * 2048 + lane * 8;
    const unsigned short* vp = wsb + OV + ((size_t)(j * 4 + b)) * FR_IB +
                               (size_t)(w * 18) * 2048 + lane * 8;

    bf16x8 bq0 = *(const bf16x8*)(qtf + 0);
    bf16x8 bq1 = *(const bf16x8*)(qtf + 512);
    bf16x8 bq2 = *(const bf16x8*)(qtf + 1024);
    bf16x8 bq3 = *(const bf16x8*)(qtf + 1536);

    f32x16 o0 = {}, o1 = {};
    float l_loc = 0.f;

    // one 32-key step: K frags in regs; V loaded just-in-time
    auto compute_step = [&](bf16x8 k0, bf16x8 k1, bf16x8 k2, bf16x8 k3,
                            int step) {
        const unsigned short* vb = vp + (size_t)step * 2048;
        bf16x8 v00 = *(const bf16x8*)(vb + 0 * 512);  // c0,rb0
        bf16x8 v10 = *(const bf16x8*)(vb + 1 * 512);  // c0,rb1
        bf16x8 v01 = *(const bf16x8*)(vb + 2 * 512);  // c1,rb0
        bf16x8 v11 = *(const bf16x8*)(vb + 3 * 512);  // c1,rb1

        f32x16 s = {};
        s = __builtin_amdgcn_mfma_f32_32x32x16_bf16(k0, bq0, s, 0, 0, 0);
        s = __builtin_amdgcn_mfma_f32_32x32x16_bf16(k1, bq1, s, 0, 0, 0);
        s = __builtin_amdgcn_mfma_f32_32x32x16_bf16(k2, bq2, s, 0, 0, 0);
        s = __builtin_amdgcn_mfma_f32_32x32x16_bf16(k3, bq3, s, 0, 0, 0);

        // raw v_exp_f32 — inputs bounded (|S|log2e <= ~12)
        #pragma unroll
        for (int r = 0; r < 16; ++r) s[r] = EXP2(s[r]);
        l_loc += ((s[0] + s[1]) + (s[2] + s[3])) + ((s[4] + s[5]) + (s[6] + s[7])) +
                 ((s[8] + s[9]) + (s[10] + s[11])) + ((s[12] + s[13]) + (s[14] + s[15]));

        {   // keys 0..15
            unsigned int a0 = pk_bf16(s[0], s[1]);
            unsigned int a1 = pk_bf16(s[2], s[3]);
            unsigned int b0 = pk_bf16(s[4], s[5]);
            unsigned int b1 = pk_bf16(s[6], s[7]);
            uintx2 r0 = __builtin_amdgcn_permlane32_swap(a0, b0, false, false);
            uintx2 r1 = __builtin_amdgcn_permlane32_swap(a1, b1, false, false);
            uintx4 pwv = {r0[0], r1[0], r0[1], r1[1]};
            bf16x8 pa = __builtin_bit_cast(bf16x8, pwv);
            o0 = __builtin_amdgcn_mfma_f32_32x32x16_bf16(v00, pa, o0, 0, 0, 0);
            o1 = __builtin_amdgcn_mfma_f32_32x32x16_bf16(v10, pa, o1, 0, 0, 0);
        }
        {   // keys 16..31
            unsigned int a0 = pk_bf16(s[8], s[9]);
            unsigned int a1 = pk_bf16(s[10], s[11]);
            unsigned int b0 = pk_bf16(s[12], s[13]);
            unsigned int b1 = pk_bf16(s[14], s[15]);
            uintx2 r0 = __builtin_amdgcn_permlane32_swap(a0, b0, false, false);
            uintx2 r1 = __builtin_amdgcn_permlane32_swap(a1, b1, false, false);
            uintx4 pwv = {r0[0], r1[0], r0[1], r1[1]};
            bf16x8 pa = __builtin_bit_cast(bf16x8, pwv);
            o0 = __builtin_amdgcn_mfma_f32_32x32x16_bf16(v01, pa, o0, 0, 0, 0);
            o1 = __builtin_amdgcn_mfma_f32_32x32x16_bf16(v11, pa, o1, 0, 0, 0);
        }
    };

    // ---- K ping-pong: preload step 0 into set A ----
    bf16x8 kA0 = *(const bf16x8*)(kp + 0 * 512);
    bf16x8 kA1 = *(const bf16x8*)(kp + 1 * 512);
    bf16x8 kA2 = *(const bf16x8*)(kp + 2 * 512);
    bf16x8 kA3 = *(const bf16x8*)(kp + 3 * 512);

    for (int step = 0; step < 18; step += 2) {
        const unsigned short* kbB = kp + (size_t)(step + 1) * 2048;
        bf16x8 kB0 = *(const bf16x8*)(kbB + 0 * 512);
        bf16x8 kB1 = *(const bf16x8*)(kbB + 1 * 512);
        bf16x8 kB2 = *(const bf16x8*)(kbB + 2 * 512);
        bf16x8 kB3 = *(const bf16x8*)(kbB + 3 * 512);

        compute_step(kA0, kA1, kA2, kA3, step);

        int nx = (step + 2 < 18) ? (step + 2) : 0;
        const unsigned short* kbA = kp + (size_t)nx * 2048;
        kA0 = *(const bf16x8*)(kbA + 0 * 512);
        kA1 = *(const bf16x8*)(kbA + 1 * 512);
        kA2 = *(const bf16x8*)(kbA + 2 * 512);
        kA3 = *(const bf16x8*)(kbA + 3 * 512);

        compute_step(kB0, kB1, kB2, kB3, step + 1);
    }

    float l_full = l_loc + __shfl_xor(l_loc, 32);

    // ---- tree combine (fp32 exact): O = sum O_w / sum l_w ----
    // stage 1: waves 1,3 post to slots 0,1
    if (w & 1) {
        float* sl = fl + (w >> 1) * 2112;
        #pragma unroll
        for (int reg = 0; reg < 16; ++reg) {
            sl[reg * 64 + lane] = o0[reg];
            sl[1024 + reg * 64 + lane] = o1[reg];
        }
        sl[2048 + lane] = l_full;
    }
    __syncthreads();
    if (!(w & 1)) {
        const float* sl = fl + (w >> 1) * 2112;
        #pragma unroll
        for (int reg = 0; reg < 16; ++reg) {
            o0[reg] += sl[reg * 64 + lane];
            o1[reg] += sl[1024 + reg * 64 + lane];
        }
        l_full += sl[2048 + lane];
    }
    __syncthreads();
    // stage 2: wave 2 posts its combined partial to slot 0
    if (w == 2) {
        float* sl = fl;
        #pragma unroll
        for (int reg = 0; reg < 16; ++reg) {
            sl[reg * 64 + lane] = o0[reg];
            sl[1024 + reg * 64 + lane] = o1[reg];
        }
        sl[2048 + lane] = l_full;
    }
    __syncthreads();
    if (w != 0) return;

    #pragma unroll
    for (int reg = 0; reg < 16; ++reg) {
        o0[reg] += fl[reg * 64 + lane];
        o1[reg] += fl[1024 + reg * 64 + lane];
    }
    l_full += fl[2048 + lane];

    float inv = 1.f / l_full;
    o0 *= inv; o1 *= inv;

    // transpose O^T -> per-query rows (wave-0-local LDS reuse), write comb frags
    float* tw = fl;
    #pragma unroll
    for (int reg = 0; reg < 16; ++reg) {
        int rv = (reg & 3) + 8 * (reg >> 2) + 4 * h;
        tw[lq * 65 + rv] = o0[reg];
        tw[lq * 65 + 32 + rv] = o1[reg];
    }
    // chunk[lane*8+e] = comb[n=q0+(lane&31)][g = i*64 + ksl*16 + 8h + e]
    unsigned short* cb = wsb + OC + (size_t)j * CSTR +
                         ((size_t)((b * 72 + qp) * 12 + i * 4)) * 512;
    #pragma unroll
    for (int ksl = 0; ksl < 4; ++ksl) {
        const float* src = tw + lq * 65 + ksl * 16 + 8 * h;
        uintx4 pwv = {pk_bf16(src[0], src[1]), pk_bf16(src[2], src[3]),
                      pk_bf16(src[4], src[5]), pk_bf16(src[6], src[7])};
        *(uintx4*)(cb + ksl * 512 + lane * 8) = pwv;
    }
}

// ---------------------------------------------------------------------------
// Kernel: MFMA out-projection + sigmoid gate.
// ---------------------------------------------------------------------------
__global__ __launch_bounds__(256) void out_mfma(
    const float* __restrict__ x, const unsigned short* __restrict__ wsb,
    float* __restrict__ out)
{
    int bid = blockIdx.x;
    int ch = bid & 1;
    int nt = (bid >> 1) % 72;
    int b  = bid / 144;
    int n0 = nt * 32;
    int t = threadIdx.x;
    int w = t >> 6, lane = t & 63;
    int lq = lane & 31, h = lane >> 5;
    int rb = ch * 4 + w;

    const unsigned short* wof = wsb + OWOF + lane * 8;
    const unsigned short* cbase = wsb + OC +
        ((size_t)((b * 72 + nt) * 12)) * 512 + lane * 8;

    f32x16 acc = {};
    #pragma unroll
    for (int j = 0; j < 3; ++j) {
        const unsigned short* cj = cbase + (size_t)j * CSTR;
        #pragma unroll
        for (int ksx = 0; ksx < 12; ++ksx) {
            bf16x8 bx = *(const bf16x8*)(cj + ksx * 512);
            bf16x8 a0 = *(const bf16x8*)(wof + (ksx * 8 + rb) * 512);
            acc = __builtin_amdgcn_mfma_f32_32x32x16_bf16(a0, bx, acc, 0, 0, 0);
        }
    }

    int c0 = rb * 32;
    #pragma unroll
    for (int reg = 0; reg < 16; ++reg) {
        int c = c0 + (reg & 3) + 8 * (reg >> 2) + 4 * h;
        size_t idx = ((size_t)(b * CC + c)) * NN_ + n0 + lq;
        float sg = 1.f / (1.f + EXP2(acc[reg] * -1.44269504f));
        out[idx] = x[idx] * sg;
    }
}

extern "C" void kernel_launch(void* const* d_in, const int* in_sizes, int n_in,
                              void* d_out, int out_size, void* d_ws, size_t ws_size,
                              hipStream_t stream) {
    const float* x  = (const float*)d_in[0];
    const float* wq = (const float*)d_in[1];
    const float* wk = (const float*)d_in[2];
    const float* wv = (const float*)d_in[3];
    const float* wo = (const float*)d_in[4];
    unsigned short* wsb = (unsigned short*)d_ws;
    float* out = (float*)d_out;

    prep_kernel<<<300, 256, 0, stream>>>(x, wq, wk, wv, wo, wsb);
    proj_mfma<<<648, 256, 0, stream>>>(wsb);
    attn_kernel<<<2592, 256, 0, stream>>>(wsb);
    out_mfma<<<576, 256, 0, stream>>>(x, wsb, out);
}